// Round 5
// baseline (534.948 us; speedup 1.0000x reference)
//
#include <hip/hip_runtime.h>

#define NF 32
#define ED 64
#define NPAIR 496             // 32*31/2
#define XPAD 68               // padded LDS row stride (floats); 68%4==0 keeps 16B align
#define OUT_PER_B (NPAIR * ED)  // 31744 floats per batch element

typedef float f32x4 __attribute__((ext_vector_type(4)));  // clang vector: valid
                                                          // for nontemporal builtins

// Combined kernel (proven absmax 0.0) + NT stores (-67us vs plain, measured
// R3/R4) + BURST store phase: compute 8 float4 into regs, then 8 back-to-back
// NT stores. Theory: NT bypasses L2 aggregation, so fabric/HBM write-combining
// needs temporally-adjacent store streams; interleaved single stores gave only
// 2.7 TB/s while the pure-burst fillBuffer hits 6.27 TB/s.
__global__ __launch_bounds__(256, 4) void bilinear_kernel(
    const float* __restrict__ x, const float* __restrict__ W,
    float* __restrict__ out) {
  __shared__ float xs[NF * XPAD];   // x[b] rows, padded
  __shared__ float vs[NF * XPAD];   // vid[b] rows, padded
  __shared__ float ws[ED * ED];     // W row-major
  __shared__ int   ptab[NPAIR];     // (i<<8)|j per pair

  const int t = threadIdx.x;
  const int b = blockIdx.x;

  // Build pair table: triu_indices(32, k=1) in row-major order.
  for (int p = t; p < NPAIR; p += 256) {
    int i = 0, rem = p;
    while (rem >= (NF - 1 - i)) { rem -= (NF - 1 - i); ++i; }
    ptab[p] = (i << 8) | (i + 1 + rem);
  }

  // Stage W: 4096 floats = 1024 float4 -> 4 per thread, coalesced.
  {
    const float4* Wg = (const float4*)W;
#pragma unroll
    for (int k = 0; k < 4; ++k) {
      int c = t + k * 256;               // float4 index 0..1023
      float4 v = Wg[c];
      *(float4*)&ws[c * 4] = v;
    }
  }

  // Stage x[b]: 2048 floats = 512 float4 -> 2 per thread, coalesced, padded rows.
  {
    const float4* xg = (const float4*)(x + (size_t)b * (NF * ED));
#pragma unroll
    for (int k = 0; k < 2; ++k) {
      int c = t + k * 256;               // 0..511
      int f = c >> 4, d4 = c & 15;
      float4 v = xg[c];
      *(float4*)&xs[f * XPAD + d4 * 4] = v;
    }
  }
  __syncthreads();

  // In-LDS GEMM: vid = x[b] @ W. Per-thread tile: 2 f-rows x 4 e-cols.
  // Same accumulation order as the verified kernels -> bitwise-identical.
  {
    const int f0 = (t >> 4) * 2;         // 0,2,...,30
    const int e0 = (t & 15) * 4;         // 0,4,...,60
    float4 acc0 = {0.f, 0.f, 0.f, 0.f};
    float4 acc1 = {0.f, 0.f, 0.f, 0.f};
    const float* xr0 = &xs[f0 * XPAD];
    const float* xr1 = &xs[(f0 + 1) * XPAD];
#pragma unroll 8
    for (int d = 0; d < ED; ++d) {
      float a0 = xr0[d];
      float a1 = xr1[d];
      float4 w4 = *(const float4*)&ws[d * ED + e0];
      acc0.x += a0 * w4.x; acc0.y += a0 * w4.y;
      acc0.z += a0 * w4.z; acc0.w += a0 * w4.w;
      acc1.x += a1 * w4.x; acc1.y += a1 * w4.y;
      acc1.z += a1 * w4.z; acc1.w += a1 * w4.w;
    }
    *(float4*)&vs[f0 * XPAD + e0] = acc0;
    *(float4*)&vs[(f0 + 1) * XPAD + e0] = acc1;
  }
  __syncthreads();

  // Burst expansion: out[b][p][e] = x[b][i][e] * vid[b][j][e].
  // 31 f4/thread as 4 bursts (8,8,8,7): compute into regs, then store
  // back-to-back. Mapping identical to the verified loop:
  //   f4 = it*256 + t, it = B*8+k; p = f4>>4; e = (f4&15)*4.
  float* ob = out + (size_t)b * OUT_PER_B;
  const int g = t >> 4;          // 0..15 (p sub-index)
  const int e = (t & 15) * 4;    // e-quad 0,4,...,60
#pragma unroll
  for (int B = 0; B < 4; ++B) {
    const int len = (B < 3) ? 8 : 7;     // 31 = 8+8+8+7
    f32x4 vals[8];
    // Compute phase: all indices compile-time after unroll -> regs, no scratch.
#pragma unroll
    for (int k = 0; k < 8; ++k) {
      if (k < len) {
        int p = (B * 8 + k) * 16 + g;
        int pr = ptab[p];
        int i = pr >> 8, j = pr & 255;
        f32x4 xv = *(const f32x4*)&xs[i * XPAD + e];
        f32x4 vv = *(const f32x4*)&vs[j * XPAD + e];
        vals[k] = xv * vv;
      }
    }
    // Store phase: 8 consecutive NT dwordx4 (4KB/thread-step, contiguous/wave).
#pragma unroll
    for (int k = 0; k < 8; ++k) {
      if (k < len) {
        size_t f4 = (size_t)(B * 8 + k) * 256 + t;
        __builtin_nontemporal_store(vals[k], (f32x4*)&ob[f4 * 4]);
      }
    }
  }
}

extern "C" void kernel_launch(void* const* d_in, const int* in_sizes, int n_in,
                              void* d_out, int out_size, void* d_ws, size_t ws_size,
                              hipStream_t stream) {
  const float* x = (const float*)d_in[0];
  const float* W = (const float*)d_in[1];
  float* out = (float*)d_out;
  const int B = in_sizes[0] / (NF * ED);   // 4096
  bilinear_kernel<<<B, 256, 0, stream>>>(x, W, out);
}